// Round 7
// baseline (245.405 us; speedup 1.0000x reference)
//
#include <hip/hip_runtime.h>
#include <math.h>

// Problem constants
#define BATCH 2
#define SEQ   2048
#define NH    16
#define HD    64
#define DM    1024
#define MROWS (BATCH * SEQ)                  // 4096
#define NEL   ((size_t)MROWS * DM)           // 4 M elements (activation buffer)
#define WEL   ((size_t)DM * DM)              // 1 M elements (weight buffer)
// softmax scale folded into Q at projection: 1/sqrt(64) * log2(e)
#define SM_SCALE_LOG2E 0.18033688011112042f

typedef __bf16 bf16x8  __attribute__((ext_vector_type(8)));
typedef float  f32x16  __attribute__((ext_vector_type(16)));

#define MFMA32(a, b, c) __builtin_amdgcn_mfma_f32_32x32x16_bf16((a), (b), (c), 0, 0, 0)
#define EXP2(x) __builtin_amdgcn_exp2f(x)

// async global->LDS, 16B per lane; LDS dest = wave-uniform base + lane*16
#define GLDS16(g, s) __builtin_amdgcn_global_load_lds( \
    (const __attribute__((address_space(1))) void*)(g), \
    (__attribute__((address_space(3))) void*)(s), 16, 0, 0)

// ======================================================================
// fp32 -> bf16 converts
// ======================================================================
__global__ __launch_bounds__(256) void cvt_x(const float* __restrict__ src,
                                             __bf16* __restrict__ dst) {
    const size_t i = ((size_t)blockIdx.x * 256 + threadIdx.x) * 4;
    const float4 f = *(const float4*)&src[i];
    __bf16 b[4] = {(__bf16)f.x, (__bf16)f.y, (__bf16)f.z, (__bf16)f.w};
    *(ushort4*)&dst[i] = *(ushort4*)b;
}

__global__ __launch_bounds__(256) void cvt_w(const float* __restrict__ w0,
                                             const float* __restrict__ w1,
                                             const float* __restrict__ w2,
                                             const float* __restrict__ w3,
                                             __bf16* __restrict__ dst) {
    const int z = blockIdx.z;
    const float* src = (z == 0) ? w0 : (z == 1) ? w1 : (z == 2) ? w2 : w3;
    __bf16* d = dst + (size_t)z * WEL;
    const size_t i = ((size_t)blockIdx.x * 256 + threadIdx.x) * 4;
    const float4 f = *(const float4*)&src[i];
    __bf16 b[4] = {(__bf16)f.x, (__bf16)f.y, (__bf16)f.z, (__bf16)f.w};
    *(ushort4*)&d[i] = *(ushort4*)b;
}

// ======================================================================
// NT bf16 MFMA GEMM on 32x32x16, 64x64 wave tiles, single-barrier
// double-buffered K-loop (BK=32).
//   BM x BN block tile, TB threads; wave tile 64x64; WCOLS = BN/64.
//   Per BK iter per wave: 8 ds_read_b128 + 8 MFMA (0.06 LDS B/MAC).
// mode 1: z selects weight+output slab; bf16 store permuted to
//   (B,H,S,HD); z==0 (Q) pre-scaled; z==2 (V) dual-stored to Vt.
// mode 0: fp32 row-major M x DM store.
// 32x32 C-layout: col = lane&31, row = (reg&3) + 8*(reg>>2) + 4*(lane>>5).
// ======================================================================
template<int BM, int BN, int TB, int MINW>
__global__ __launch_bounds__(TB, MINW) void gemm_nt_mfma(
    const __bf16* __restrict__ A, const __bf16* __restrict__ W0,
    void* __restrict__ C0, __bf16* __restrict__ Vt, int mode)
{
    constexpr int NIT   = DM / 32;       // 32 K-iterations
    constexpr int W     = TB / 64;       // waves per block
    constexpr int WCOLS = BN / 64;       // wave-grid columns
    constexpr int AI    = BM / 16 / W;   // A staging instrs per wave
    constexpr int BI    = BN / 16 / W;   // B staging instrs per wave
    __shared__ __bf16 Ast[2][BM * 32];
    __shared__ __bf16 Bst[2][BN * 32];

    const int t = threadIdx.x;
    const int w = t >> 6, l = t & 63;
    const int h = l >> 5, c = l & 31;
    const int z = blockIdx.z;
    const int m0 = blockIdx.y * BM, n0 = blockIdx.x * BN;
    const int wm = (w / WCOLS) * 64;
    const int wn = (w % WCOLS) * 64;

    const __bf16* Wp = W0 + (size_t)z * WEL;

    const int lrow = l >> 2;           // staging: lane row within 16-row instr
    const int lkof = (l & 3) * 8;      // staging: lane k-offset
    const __bf16* Ag = A  + (size_t)(m0 + w * (BM / W) + lrow) * DM + lkof;
    const __bf16* Bg = Wp + (size_t)(n0 + w * (BN / W) + lrow) * DM + lkof;
    const int aoff = (w * (BM / W)) * 32;   // wave-uniform LDS offsets
    const int boff = (w * (BN / W)) * 32;

    f32x16 acc[2][2];
    #pragma unroll
    for (int i = 0; i < 2; i++)
        #pragma unroll
        for (int j = 0; j < 2; j++) acc[i][j] = (f32x16)0.0f;

    // prologue: tile 0 -> buf 0
    #pragma unroll
    for (int i = 0; i < AI; i++) GLDS16(Ag + (size_t)i * 16 * DM, &Ast[0][aoff + i * 512]);
    #pragma unroll
    for (int i = 0; i < BI; i++) GLDS16(Bg + (size_t)i * 16 * DM, &Bst[0][boff + i * 512]);
    __syncthreads();

    for (int it = 0; it < NIT; it++) {
        const int cur = it & 1, nxt = cur ^ 1;
        if (it + 1 < NIT) {
            const int k0 = (it + 1) * 32;
            #pragma unroll
            for (int i = 0; i < AI; i++)
                GLDS16(Ag + k0 + (size_t)i * 16 * DM, &Ast[nxt][aoff + i * 512]);
            #pragma unroll
            for (int i = 0; i < BI; i++)
                GLDS16(Bg + k0 + (size_t)i * 16 * DM, &Bst[nxt][boff + i * 512]);
        }

        bf16x8 af[2][2], bfr[2][2];   // [mb|nb][ks]
        #pragma unroll
        for (int mb = 0; mb < 2; mb++)
            #pragma unroll
            for (int ks = 0; ks < 2; ks++)
                af[mb][ks] = *(const bf16x8*)&Ast[cur][(wm + mb * 32 + c) * 32 + ks * 16 + h * 8];
        #pragma unroll
        for (int nb = 0; nb < 2; nb++)
            #pragma unroll
            for (int ks = 0; ks < 2; ks++)
                bfr[nb][ks] = *(const bf16x8*)&Bst[cur][(wn + nb * 32 + c) * 32 + ks * 16 + h * 8];
        #pragma unroll
        for (int ks = 0; ks < 2; ks++)
            #pragma unroll
            for (int mb = 0; mb < 2; mb++)
                #pragma unroll
                for (int nb = 0; nb < 2; nb++)
                    acc[mb][nb] = MFMA32(af[mb][ks], bfr[nb][ks], acc[mb][nb]);

        __syncthreads();   // single barrier: drains prefetch, fences buffers
    }

    if (mode) {
        const float sc = (z == 0) ? SM_SCALE_LOG2E : 1.0f;
        __bf16* C = (__bf16*)C0 + (size_t)z * NEL;
        #pragma unroll
        for (int mb = 0; mb < 2; mb++)
            #pragma unroll
            for (int nb = 0; nb < 2; nb++)
                #pragma unroll
                for (int g = 0; g < 4; g++)
                    #pragma unroll
                    for (int rr = 0; rr < 4; rr++) {
                        const int row = m0 + wm + mb * 32 + rr + 8 * g + 4 * h;
                        const int col = n0 + wn + nb * 32 + c;
                        const int b = row >> 11, s = row & (SEQ - 1);
                        const int hh = col >> 6, d = col & (HD - 1);
                        const __bf16 val = (__bf16)(acc[mb][nb][4 * g + rr] * sc);
                        C[((size_t)(b * NH + hh) * SEQ + s) * HD + d] = val;
                        if (z == 2)   // V: also store transposed (B,H,HD,S)
                            Vt[((size_t)(b * NH + hh) * HD + d) * SEQ + s] = val;
                    }
    } else {
        float* C = (float*)C0;
        #pragma unroll
        for (int mb = 0; mb < 2; mb++)
            #pragma unroll
            for (int nb = 0; nb < 2; nb++)
                #pragma unroll
                for (int g = 0; g < 4; g++)
                    #pragma unroll
                    for (int rr = 0; rr < 4; rr++) {
                        const int row = m0 + wm + mb * 32 + rr + 8 * g + 4 * h;
                        const int col = n0 + wn + nb * 32 + c;
                        C[(size_t)row * DM + col] = acc[mb][nb][4 * g + rr];
                    }
    }
}

// ======================================================================
// Flash attention v6 on 32x32x16 MFMA. Block = 256 queries of one (b,h),
// 4 waves x 64 queries (2 query-blocks of 32). K-tiles of 64 keys,
// shared dbuf staging, single barrier per tile. Q loaded global->regs
// (no Q LDS). Fixed-shift softmax (Q pre-scaled by 1/sqrt(64)*log2e).
// Per wave-iter: QK 16 MFMA (8 kf b128 reads), P 16 b64 writes + 8 b128
// reads, PV 16 MFMA (8 vf b128 reads) -> 0.06 LDS B/MAC.
// Epilogue: normalize by l, fused subtract-projection, store X2 (B,S,DM).
// ======================================================================
__global__ __launch_bounds__(256, 1) void attn_mfma(
    const __bf16* __restrict__ Q, const __bf16* __restrict__ K,
    const __bf16* __restrict__ Vt, const __bf16* __restrict__ V,
    const float* __restrict__ xsa, __bf16* __restrict__ X2)
{
    __shared__ __bf16 Ks[2][2][64][32];  // [buf][dimhalf][key][dim32] 16 KB
    __shared__ __bf16 Vs[2][2][64][32];  // [buf][keyhalf][dim][key32] 16 KB
    __shared__ __bf16 Pt[4][2][64][32];  // [wave][keyhalf][q][key32]  32 KB

    const int t = threadIdx.x;
    const int w = t >> 6, l = t & 63;
    const int h = l >> 5, c = l & 31;
    const int bh = blockIdx.y;
    const int q0 = blockIdx.x * 256;

    const __bf16* Qb  = Q  + (size_t)bh * SEQ * HD;
    const __bf16* Kb  = K  + (size_t)bh * SEQ * HD;
    const __bf16* Vtb = Vt + (size_t)bh * HD * SEQ;

    const int lrow = l >> 2;
    const int lkof = (l & 3) * 8;

    // ---- Q fragments: direct global -> registers (loop-invariant) ----
    bf16x8 qf[2][4];   // [qb][ks]
    #pragma unroll
    for (int qb = 0; qb < 2; qb++)
        #pragma unroll
        for (int ks = 0; ks < 4; ks++)
            qf[qb][ks] = *(const bf16x8*)&Qb[(size_t)(q0 + w * 64 + qb * 32 + c) * HD
                                             + ks * 16 + h * 8];

    // ---- prologue: stage K0/V0 into buf 0 (4 GLDS per wave) ----
    #pragma unroll
    for (int dh = 0; dh < 2; dh++)
        GLDS16(Kb + (size_t)(w * 16 + lrow) * HD + dh * 32 + lkof,
               &Ks[0][dh][w * 16][0]);
    #pragma unroll
    for (int kh = 0; kh < 2; kh++)
        GLDS16(Vtb + (size_t)(w * 16 + lrow) * SEQ + kh * 32 + lkof,
               &Vs[0][kh][w * 16][0]);
    __syncthreads();

    float l_i[2] = {0.0f, 0.0f};
    f32x16 o[2][2];   // [db][qb]
    #pragma unroll
    for (int db = 0; db < 2; db++)
        #pragma unroll
        for (int qb = 0; qb < 2; qb++) o[db][qb] = (f32x16)0.0f;

    constexpr int NTILES = SEQ / 64;   // 32 key tiles
    for (int kt = 0; kt < NTILES; kt++) {
        const int cur = kt & 1, nxt = cur ^ 1;
        if (kt + 1 < NTILES) {
            const int k0n = (kt + 1) * 64;
            #pragma unroll
            for (int dh = 0; dh < 2; dh++)
                GLDS16(Kb + (size_t)(k0n + w * 16 + lrow) * HD + dh * 32 + lkof,
                       &Ks[nxt][dh][w * 16][0]);
            #pragma unroll
            for (int kh = 0; kh < 2; kh++)
                GLDS16(Vtb + (size_t)(w * 16 + lrow) * SEQ + k0n + kh * 32 + lkof,
                       &Vs[nxt][kh][w * 16][0]);
        }

        // ---- S^T = K Q^T : 64k x 64q x 64d per wave (16 MFMAs) ----
        f32x16 st[2][2];   // [qb][kb]
        #pragma unroll
        for (int qb = 0; qb < 2; qb++)
            #pragma unroll
            for (int kb = 0; kb < 2; kb++) st[qb][kb] = (f32x16)0.0f;
        #pragma unroll
        for (int ks = 0; ks < 4; ks++) {
            bf16x8 kf[2];
            #pragma unroll
            for (int kb = 0; kb < 2; kb++)
                kf[kb] = *(const bf16x8*)&Ks[cur][ks >> 1][kb * 32 + c][(ks & 1) * 16 + h * 8];
            #pragma unroll
            for (int qb = 0; qb < 2; qb++)
                #pragma unroll
                for (int kb = 0; kb < 2; kb++)
                    st[qb][kb] = MFMA32(kf[kb], qf[qb][ks], st[qb][kb]);
        }

        // ---- fixed-shift softmax: p = exp2(s); P -> per-wave LDS ----
        #pragma unroll
        for (int qb = 0; qb < 2; qb++) {
            float rs = 0.0f;
            #pragma unroll
            for (int kb = 0; kb < 2; kb++)
                #pragma unroll
                for (int r = 0; r < 16; r++) {
                    const float p = EXP2(st[qb][kb][r]);
                    st[qb][kb][r] = p;
                    rs += p;
                }
            rs += __shfl_xor(rs, 32);
            l_i[qb] += rs;
            #pragma unroll
            for (int kb = 0; kb < 2; kb++)
                #pragma unroll
                for (int g = 0; g < 4; g++) {
                    __bf16 pb[4] = {(__bf16)st[qb][kb][4 * g + 0], (__bf16)st[qb][kb][4 * g + 1],
                                    (__bf16)st[qb][kb][4 * g + 2], (__bf16)st[qb][kb][4 * g + 3]};
                    *(uint2*)&Pt[w][kb][qb * 32 + c][4 * h + 8 * g] = *(uint2*)pb;
                }
        }

        // ---- O^T += V^T P : 64d x 64q x 64k per wave (16 MFMAs) ----
        #pragma unroll
        for (int ks = 0; ks < 4; ks++) {
            bf16x8 vf[2], pf[2];
            #pragma unroll
            for (int db = 0; db < 2; db++)
                vf[db] = *(const bf16x8*)&Vs[cur][ks >> 1][db * 32 + c][(ks & 1) * 16 + h * 8];
            #pragma unroll
            for (int qb = 0; qb < 2; qb++)
                pf[qb] = *(const bf16x8*)&Pt[w][ks >> 1][qb * 32 + c][(ks & 1) * 16 + h * 8];
            #pragma unroll
            for (int db = 0; db < 2; db++)
                #pragma unroll
                for (int qb = 0; qb < 2; qb++)
                    o[db][qb] = MFMA32(vf[db], pf[qb], o[db][qb]);
        }

        __syncthreads();   // single barrier: drains prefetch, fences buffers
    }

    // ---- epilogue: normalize, fused subtract-projection, store X2 ----
    const float xs = xsa[0];
    const int b = bh >> 4, hh = bh & (NH - 1);
    const __bf16* Vb = V + (size_t)bh * SEQ * HD;
    #pragma unroll
    for (int qb = 0; qb < 2; qb++) {
        const int q = q0 + w * 64 + qb * 32 + c;   // sequence position
        const float inv = 1.0f / l_i[qb];
        float vv[2][4][4];
        float dp = 0.0f, nn = 0.0f;
        #pragma unroll
        for (int db = 0; db < 2; db++)
            #pragma unroll
            for (int g = 0; g < 4; g++) {
                __bf16 vb4[4];
                *(uint2*)vb4 = *(const uint2*)&Vb[(size_t)q * HD + db * 32 + 8 * g + 4 * h];
                #pragma unroll
                for (int rr = 0; rr < 4; rr++) {
                    const float vf = (float)vb4[rr];
                    const float of = o[db][qb][4 * g + rr] * inv;
                    vv[db][g][rr] = vf;
                    dp += of * vf;
                    nn += vf * vf;
                }
            }
        dp += __shfl_xor(dp, 32);
        nn += __shfl_xor(nn, 32);
        const float coef = xs * dp / (nn + 1e-8f);
        #pragma unroll
        for (int db = 0; db < 2; db++)
            #pragma unroll
            for (int g = 0; g < 4; g++) {
                __bf16 ob[4];
                #pragma unroll
                for (int rr = 0; rr < 4; rr++)
                    ob[rr] = (__bf16)(o[db][qb][4 * g + rr] * inv - coef * vv[db][g][rr]);
                *(uint2*)&X2[((size_t)b * SEQ + q) * DM + hh * HD + db * 32 + 8 * g + 4 * h] =
                    *(uint2*)ob;
            }
    }
}

// ======================================================================
extern "C" void kernel_launch(void* const* d_in, const int* in_sizes, int n_in,
                              void* d_out, int out_size, void* d_ws, size_t ws_size,
                              hipStream_t stream)
{
    (void)in_sizes; (void)n_in; (void)out_size; (void)ws_size;
    const float* x   = (const float*)d_in[0];
    const float* Wq  = (const float*)d_in[1];
    const float* Wk  = (const float*)d_in[2];
    const float* Wv  = (const float*)d_in[3];
    const float* Wo  = (const float*)d_in[4];
    const float* xsa = (const float*)d_in[5];
    float* out = (float*)d_out;

    // workspace layout (bf16 elements): 56 MB total
    __bf16* xb  = (__bf16*)d_ws;        // 4 M
    __bf16* Wb  = xb  + NEL;            // 4 x 1 M (Wq,Wk,Wv,Wo)
    __bf16* Qb  = Wb  + 4 * WEL;        // 4 M  (B,H,S,HD), pre-scaled
    __bf16* Kb  = Qb  + NEL;            // 4 M
    __bf16* Vb  = Kb  + NEL;            // 4 M
    __bf16* Vtb = Vb  + NEL;            // 4 M  (B,H,HD,S)
    __bf16* X2  = Vtb + NEL;            // 4 M  (B,S,DM)

    cvt_x<<<dim3(NEL / 1024), 256, 0, stream>>>(x, xb);
    cvt_w<<<dim3(WEL / 1024, 1, 4), 256, 0, stream>>>(Wq, Wk, Wv, Wo, Wb);

    // Q/K/V projections: 128x128 tile, 4 waves of 64x64, grid 768 = 3/CU
    gemm_nt_mfma<128, 128, 256, 3>
        <<<dim3(DM / 128, MROWS / 128, 3), 256, 0, stream>>>(xb, Wb, Qb, Vtb, 1);

    // attention + fused subtract-projection -> X2 (256q blocks, grid 256)
    attn_mfma<<<dim3(SEQ / 256, BATCH * NH), 256, 0, stream>>>(
        Qb, Kb, Vtb, Vb, xsa, X2);

    // output projection: 128x64 tile, 2 waves, grid 512 = 2/CU, fp32 out
    gemm_nt_mfma<128, 64, 128, 2>
        <<<dim3(DM / 64, MROWS / 128, 1), 128, 0, stream>>>(
        X2, Wb + 3 * WEL, out, nullptr, 0);
}

// Round 8
// 211.628 us; speedup vs baseline: 1.1596x; 1.1596x over previous
//
#include <hip/hip_runtime.h>
#include <math.h>

// Problem constants
#define BATCH 2
#define SEQ   2048
#define NH    16
#define HD    64
#define DM    1024
#define MROWS (BATCH * SEQ)                  // 4096
#define NEL   ((size_t)MROWS * DM)           // 4 M elements (activation buffer)
#define WEL   ((size_t)DM * DM)              // 1 M elements (weight buffer)
// softmax scale folded into Q at projection: 1/sqrt(64) * log2(e)
#define SM_SCALE_LOG2E 0.18033688011112042f

typedef __bf16 bf16x8  __attribute__((ext_vector_type(8)));
typedef float  f32x4   __attribute__((ext_vector_type(4)));
typedef float  f32x16  __attribute__((ext_vector_type(16)));

#define MFMA16(a, b, c) __builtin_amdgcn_mfma_f32_16x16x32_bf16((a), (b), (c), 0, 0, 0)
#define MFMA32(a, b, c) __builtin_amdgcn_mfma_f32_32x32x16_bf16((a), (b), (c), 0, 0, 0)
#define EXP2(x) __builtin_amdgcn_exp2f(x)

// async global->LDS, 16B per lane; LDS dest = wave-uniform base + lane*16
#define GLDS16(g, s) __builtin_amdgcn_global_load_lds( \
    (const __attribute__((address_space(1))) void*)(g), \
    (__attribute__((address_space(3))) void*)(s), 16, 0, 0)

// ======================================================================
// fp32 -> bf16 converts
// ======================================================================
__global__ __launch_bounds__(256) void cvt_x(const float* __restrict__ src,
                                             __bf16* __restrict__ dst) {
    const size_t i = ((size_t)blockIdx.x * 256 + threadIdx.x) * 4;
    const float4 f = *(const float4*)&src[i];
    __bf16 b[4] = {(__bf16)f.x, (__bf16)f.y, (__bf16)f.z, (__bf16)f.w};
    *(ushort4*)&dst[i] = *(ushort4*)b;
}

__global__ __launch_bounds__(256) void cvt_w(const float* __restrict__ w0,
                                             const float* __restrict__ w1,
                                             const float* __restrict__ w2,
                                             const float* __restrict__ w3,
                                             __bf16* __restrict__ dst) {
    const int z = blockIdx.z;
    const float* src = (z == 0) ? w0 : (z == 1) ? w1 : (z == 2) ? w2 : w3;
    __bf16* d = dst + (size_t)z * WEL;
    const size_t i = ((size_t)blockIdx.x * 256 + threadIdx.x) * 4;
    const float4 f = *(const float4*)&src[i];
    __bf16 b[4] = {(__bf16)f.x, (__bf16)f.y, (__bf16)f.z, (__bf16)f.w};
    *(ushort4*)&d[i] = *(ushort4*)b;
}

// ======================================================================
// NT bf16 MFMA GEMM on 32x32x16, 64x64 wave tiles, single-barrier
// double-buffered K-loop (BK=32), XOR-SWIZZLED LDS:
//   Each 64B LDS row holds 4 x 16B chunks; chunk slot s of row r holds
//   global chunk s ^ (r&3). Staging permutes only the GLOBAL source
//   address per lane (GLDS16's lane-contiguous LDS dest is preserved);
//   fragment reads use chunk (2ks+h) ^ (c&3). Bank check: each b128
//   fragment read covers all 32 banks x 8 words (was 16 banks x 16 ->
//   2x conflict in R7).
// mode 1: z selects weight+output slab; bf16 store permuted to
//   (B,H,S,HD); z==0 (Q) pre-scaled; z==2 (V) dual-stored to Vt.
// mode 0: fp32 row-major M x DM store.
// 32x32 C-layout: col = lane&31, row = (reg&3) + 8*(reg>>2) + 4*(lane>>5).
// ======================================================================
template<int BM, int BN, int TB, int MINW>
__global__ __launch_bounds__(TB, MINW) void gemm_nt_mfma(
    const __bf16* __restrict__ A, const __bf16* __restrict__ W0,
    void* __restrict__ C0, __bf16* __restrict__ Vt, int mode)
{
    constexpr int NIT   = DM / 32;       // 32 K-iterations
    constexpr int W     = TB / 64;       // waves per block
    constexpr int WCOLS = BN / 64;       // wave-grid columns
    constexpr int AI    = BM / 16 / W;   // A staging instrs per wave
    constexpr int BI    = BN / 16 / W;   // B staging instrs per wave
    __shared__ __bf16 Ast[2][BM * 32];
    __shared__ __bf16 Bst[2][BN * 32];

    const int t = threadIdx.x;
    const int w = t >> 6, l = t & 63;
    const int h = l >> 5, c = l & 31;
    const int z = blockIdx.z;
    const int m0 = blockIdx.y * BM, n0 = blockIdx.x * BN;
    const int wm = (w / WCOLS) * 64;
    const int wn = (w % WCOLS) * 64;

    const __bf16* Wp = W0 + (size_t)z * WEL;

    const int lrow = l >> 2;                       // staging row within instr
    const int lkof = (((l & 3) ^ (lrow & 3)) * 8); // XOR-swizzled chunk
    const __bf16* Ag = A  + (size_t)(m0 + w * (BM / W) + lrow) * DM + lkof;
    const __bf16* Bg = Wp + (size_t)(n0 + w * (BN / W) + lrow) * DM + lkof;
    const int aoff = (w * (BM / W)) * 32;   // wave-uniform LDS offsets
    const int boff = (w * (BN / W)) * 32;

    f32x16 acc[2][2];
    #pragma unroll
    for (int i = 0; i < 2; i++)
        #pragma unroll
        for (int j = 0; j < 2; j++) acc[i][j] = (f32x16)0.0f;

    // prologue: tile 0 -> buf 0
    #pragma unroll
    for (int i = 0; i < AI; i++) GLDS16(Ag + (size_t)i * 16 * DM, &Ast[0][aoff + i * 512]);
    #pragma unroll
    for (int i = 0; i < BI; i++) GLDS16(Bg + (size_t)i * 16 * DM, &Bst[0][boff + i * 512]);
    __syncthreads();

    for (int it = 0; it < NIT; it++) {
        const int cur = it & 1, nxt = cur ^ 1;
        if (it + 1 < NIT) {
            const int k0 = (it + 1) * 32;
            #pragma unroll
            for (int i = 0; i < AI; i++)
                GLDS16(Ag + k0 + (size_t)i * 16 * DM, &Ast[nxt][aoff + i * 512]);
            #pragma unroll
            for (int i = 0; i < BI; i++)
                GLDS16(Bg + k0 + (size_t)i * 16 * DM, &Bst[nxt][boff + i * 512]);
        }

        bf16x8 af[2][2], bfr[2][2];   // [mb|nb][ks]
        #pragma unroll
        for (int mb = 0; mb < 2; mb++)
            #pragma unroll
            for (int ks = 0; ks < 2; ks++)
                af[mb][ks] = *(const bf16x8*)&Ast[cur][(wm + mb * 32 + c) * 32
                                 + ((2 * ks + h) ^ (c & 3)) * 8];
        #pragma unroll
        for (int nb = 0; nb < 2; nb++)
            #pragma unroll
            for (int ks = 0; ks < 2; ks++)
                bfr[nb][ks] = *(const bf16x8*)&Bst[cur][(wn + nb * 32 + c) * 32
                                  + ((2 * ks + h) ^ (c & 3)) * 8];
        #pragma unroll
        for (int ks = 0; ks < 2; ks++)
            #pragma unroll
            for (int mb = 0; mb < 2; mb++)
                #pragma unroll
                for (int nb = 0; nb < 2; nb++)
                    acc[mb][nb] = MFMA32(af[mb][ks], bfr[nb][ks], acc[mb][nb]);

        __syncthreads();   // single barrier: drains prefetch, fences buffers
    }

    if (mode) {
        const float sc = (z == 0) ? SM_SCALE_LOG2E : 1.0f;
        __bf16* C = (__bf16*)C0 + (size_t)z * NEL;
        #pragma unroll
        for (int mb = 0; mb < 2; mb++)
            #pragma unroll
            for (int nb = 0; nb < 2; nb++)
                #pragma unroll
                for (int g = 0; g < 4; g++)
                    #pragma unroll
                    for (int rr = 0; rr < 4; rr++) {
                        const int row = m0 + wm + mb * 32 + rr + 8 * g + 4 * h;
                        const int col = n0 + wn + nb * 32 + c;
                        const int b = row >> 11, s = row & (SEQ - 1);
                        const int hh = col >> 6, d = col & (HD - 1);
                        const __bf16 val = (__bf16)(acc[mb][nb][4 * g + rr] * sc);
                        C[((size_t)(b * NH + hh) * SEQ + s) * HD + d] = val;
                        if (z == 2)   // V: also store transposed (B,H,HD,S)
                            Vt[((size_t)(b * NH + hh) * HD + d) * SEQ + s] = val;
                    }
    } else {
        float* C = (float*)C0;
        #pragma unroll
        for (int mb = 0; mb < 2; mb++)
            #pragma unroll
            for (int nb = 0; nb < 2; nb++)
                #pragma unroll
                for (int g = 0; g < 4; g++)
                    #pragma unroll
                    for (int rr = 0; rr < 4; rr++) {
                        const int row = m0 + wm + mb * 32 + rr + 8 * g + 4 * h;
                        const int col = n0 + wn + nb * 32 + c;
                        C[(size_t)row * DM + col] = acc[mb][nb][4 * g + rr];
                    }
    }
}

// ======================================================================
// Flash attention (R5 config, best measured: 63.9 us): 16x16x32 MFMA,
// transposed-score formulation, fixed-shift softmax, fused
// subtract-projection, Q-in-registers, single-barrier dbuf K/V staging.
// Block = 128 queries of one (b,h), 4 waves x 32 q. All LDS access
// patterns verified conflict-free by bank arithmetic.
// ======================================================================
__global__ __launch_bounds__(256, 3) void attn_mfma(
    const __bf16* __restrict__ Q, const __bf16* __restrict__ K,
    const __bf16* __restrict__ Vt, const __bf16* __restrict__ V,
    const float* __restrict__ xsa, __bf16* __restrict__ X2)
{
    // KV[buf][0] = K region [half][key][32]; KV[buf][1] = V region
    // [keyhalf][dim][32]. Each region 4096 elems (8 KB).
    __shared__ __bf16 KV[2][2][2 * 64 * 32];
    __shared__ __bf16 Pt[4][32][72];   // per-wave P [q][key+pad]  18 KB

    const int t = threadIdx.x;
    const int w = t >> 6, l = t & 63;
    const int quad = l >> 4, l15 = l & 15;
    const int bh = blockIdx.y;
    const int q0 = blockIdx.x * 128;

    const __bf16* Qb  = Q  + (size_t)bh * SEQ * HD;
    const __bf16* Kb  = K  + (size_t)bh * SEQ * HD;
    const __bf16* Vtb = Vt + (size_t)bh * HD * SEQ;

    const int lrow = l >> 2;
    const int lkof = (l & 3) * 8;

    // ---- prologue: stage Q into KV[1] (16 KB overlay) + K0/V0 into KV[0]
    __bf16* Qst = &KV[1][0][0];   // flat [h][q][32]: h*4096 + q*32
    #pragma unroll
    for (int h = 0; h < 2; h++)
        #pragma unroll
        for (int qq = 0; qq < 2; qq++)
            GLDS16(Qb + (size_t)(q0 + w * 32 + qq * 16 + lrow) * HD + h * 32 + lkof,
                   Qst + h * 4096 + (w * 32 + qq * 16) * 32);
    #pragma unroll
    for (int h = 0; h < 2; h++)
        GLDS16(Kb + (size_t)(w * 16 + lrow) * HD + h * 32 + lkof,
               &KV[0][0][h * 2048 + (w * 16) * 32]);
    #pragma unroll
    for (int kh = 0; kh < 2; kh++)
        GLDS16(Vtb + (size_t)(w * 16 + lrow) * SEQ + kh * 32 + lkof,
               &KV[0][1][kh * 2048 + (w * 16) * 32]);
    __syncthreads();   // all prologue staging visible

    // ---- hoist Q fragments to registers (loop-invariant) ----
    bf16x8 qf[2][2];   // [half][mi]
    #pragma unroll
    for (int h = 0; h < 2; h++)
        #pragma unroll
        for (int mi = 0; mi < 2; mi++)
            qf[h][mi] = *(const bf16x8*)&Qst[h * 4096 +
                          (w * 32 + mi * 16 + l15) * 32 + quad * 8];
    __syncthreads();   // Q reads done before kt=0 prefetch overwrites KV[1]

    float l_i[2] = {0.0f, 0.0f};
    f32x4 o[2][4];
    #pragma unroll
    for (int mi = 0; mi < 2; mi++)
        #pragma unroll
        for (int db = 0; db < 4; db++) o[mi][db] = (f32x4)0.0f;

    constexpr int NTILES = SEQ / 64;   // 32 key tiles
    for (int kt = 0; kt < NTILES; kt++) {
        const int cur = kt & 1, nxt = cur ^ 1;
        if (kt + 1 < NTILES) {
            const int k0n = (kt + 1) * 64;
            #pragma unroll
            for (int h = 0; h < 2; h++)
                GLDS16(Kb + (size_t)(k0n + w * 16 + lrow) * HD + h * 32 + lkof,
                       &KV[nxt][0][h * 2048 + (w * 16) * 32]);
            #pragma unroll
            for (int kh = 0; kh < 2; kh++)
                GLDS16(Vtb + (size_t)(w * 16 + lrow) * SEQ + k0n + kh * 32 + lkof,
                       &KV[nxt][1][kh * 2048 + (w * 16) * 32]);
        }
        const __bf16* Ks = &KV[cur][0][0];
        const __bf16* Vs = &KV[cur][1][0];

        // ---- S^T = K Q^T : 64k x 32q x 64d per wave (16 MFMAs) ----
        f32x4 st[2][4];
        #pragma unroll
        for (int mi = 0; mi < 2; mi++)
            #pragma unroll
            for (int kb = 0; kb < 4; kb++) st[mi][kb] = (f32x4)0.0f;
        #pragma unroll
        for (int h = 0; h < 2; h++)
            #pragma unroll
            for (int kb = 0; kb < 4; kb++) {
                const bf16x8 kf = *(const bf16x8*)&Ks[h * 2048 +
                                      (kb * 16 + l15) * 32 + quad * 8];
                #pragma unroll
                for (int mi = 0; mi < 2; mi++)
                    st[mi][kb] = MFMA16(kf, qf[h][mi], st[mi][kb]);
            }

        // ---- fixed-shift softmax: p = exp2(s), accumulate l ----
        #pragma unroll
        for (int mi = 0; mi < 2; mi++) {
            float rs = 0.0f;
            #pragma unroll
            for (int kb = 0; kb < 4; kb++)
                #pragma unroll
                for (int r = 0; r < 4; r++) {
                    const float p = EXP2(st[mi][kb][r]);
                    st[mi][kb][r] = p;
                    rs += p;
                }
            rs += __shfl_xor(rs, 16);
            rs += __shfl_xor(rs, 32);
            l_i[mi] += rs;
            #pragma unroll
            for (int kb = 0; kb < 4; kb++) {
                __bf16 pb[4] = {(__bf16)st[mi][kb][0], (__bf16)st[mi][kb][1],
                                (__bf16)st[mi][kb][2], (__bf16)st[mi][kb][3]};
                *(uint2*)&Pt[w][mi * 16 + l15][kb * 16 + quad * 4] = *(uint2*)pb;
            }
        }

        // ---- O^T += V^T P^T : 64d x 32q x 64k per wave (16 MFMAs) ----
        #pragma unroll
        for (int kh = 0; kh < 2; kh++) {
            bf16x8 pf[2];
            #pragma unroll
            for (int mi = 0; mi < 2; mi++)
                pf[mi] = *(const bf16x8*)&Pt[w][mi * 16 + l15][kh * 32 + quad * 8];
            #pragma unroll
            for (int db = 0; db < 4; db++) {
                const bf16x8 vf = *(const bf16x8*)&Vs[kh * 2048 +
                                      (db * 16 + l15) * 32 + quad * 8];
                #pragma unroll
                for (int mi = 0; mi < 2; mi++)
                    o[mi][db] = MFMA16(vf, pf[mi], o[mi][db]);
            }
        }

        __syncthreads();   // single barrier: drains prefetch, fences buffers
    }

    // ---- epilogue: normalize, fused subtract-projection, store X2 ----
    const float xs = xsa[0];
    const int b = bh >> 4, h = bh & (NH - 1);
    const __bf16* Vb = V + (size_t)bh * SEQ * HD;
    #pragma unroll
    for (int mi = 0; mi < 2; mi++) {
        const int q = q0 + w * 32 + mi * 16 + l15;   // sequence position
        const float inv = 1.0f / l_i[mi];
        float vv[4][4], on[4][4];
        float dp = 0.0f, nn = 0.0f;
        #pragma unroll
        for (int db = 0; db < 4; db++) {
            __bf16 vb4[4];
            *(uint2*)vb4 = *(const uint2*)&Vb[(size_t)q * HD + db * 16 + quad * 4];
            #pragma unroll
            for (int r = 0; r < 4; r++) {
                const float vf = (float)vb4[r];
                const float of = o[mi][db][r] * inv;
                vv[db][r] = vf;
                on[db][r] = of;
                dp += of * vf;
                nn += vf * vf;
            }
        }
        dp += __shfl_xor(dp, 16); dp += __shfl_xor(dp, 32);
        nn += __shfl_xor(nn, 16); nn += __shfl_xor(nn, 32);
        const float coef = xs * dp / (nn + 1e-8f);
        #pragma unroll
        for (int db = 0; db < 4; db++) {
            __bf16 ob[4];
            #pragma unroll
            for (int r = 0; r < 4; r++)
                ob[r] = (__bf16)(on[db][r] - coef * vv[db][r]);
            *(uint2*)&X2[((size_t)b * SEQ + q) * DM + h * HD + db * 16 + quad * 4] =
                *(uint2*)ob;
        }
    }
}

// ======================================================================
extern "C" void kernel_launch(void* const* d_in, const int* in_sizes, int n_in,
                              void* d_out, int out_size, void* d_ws, size_t ws_size,
                              hipStream_t stream)
{
    (void)in_sizes; (void)n_in; (void)out_size; (void)ws_size;
    const float* x   = (const float*)d_in[0];
    const float* Wq  = (const float*)d_in[1];
    const float* Wk  = (const float*)d_in[2];
    const float* Wv  = (const float*)d_in[3];
    const float* Wo  = (const float*)d_in[4];
    const float* xsa = (const float*)d_in[5];
    float* out = (float*)d_out;

    // workspace layout (bf16 elements): 56 MB total
    __bf16* xb  = (__bf16*)d_ws;        // 4 M
    __bf16* Wb  = xb  + NEL;            // 4 x 1 M (Wq,Wk,Wv,Wo)
    __bf16* Qb  = Wb  + 4 * WEL;        // 4 M  (B,H,S,HD), pre-scaled
    __bf16* Kb  = Qb  + NEL;            // 4 M
    __bf16* Vb  = Kb  + NEL;            // 4 M
    __bf16* Vtb = Vb  + NEL;            // 4 M  (B,H,HD,S)
    __bf16* X2  = Vtb + NEL;            // 4 M  (B,S,DM)

    cvt_x<<<dim3(NEL / 1024), 256, 0, stream>>>(x, xb);
    cvt_w<<<dim3(WEL / 1024, 1, 4), 256, 0, stream>>>(Wq, Wk, Wv, Wo, Wb);

    // Q/K/V projections: 128x128 tile, 4 waves of 64x64, swizzled LDS,
    // grid 768 = 3 blocks/CU = 12 waves/CU
    gemm_nt_mfma<128, 128, 256, 3>
        <<<dim3(DM / 128, MROWS / 128, 3), 256, 0, stream>>>(xb, Wb, Qb, Vtb, 1);

    // attention + fused subtract-projection -> X2 (R5 config, grid 512)
    attn_mfma<<<dim3(SEQ / 128, BATCH * NH), 256, 0, stream>>>(
        Qb, Kb, Vtb, Vb, xsa, X2);

    // output projection: 64x64 single-wave blocks, grid 1024 -> many
    // independent dbuf pipelines/CU; redundant re-reads are L3-resident
    gemm_nt_mfma<64, 64, 64, 3>
        <<<dim3(DM / 64, MROWS / 64, 1), 64, 0, stream>>>(
        X2, Wb + 3 * WEL, out, nullptr, 0);
}